// Round 3
// baseline (33.109 us; speedup 1.0000x reference)
//
#include <hip/hip_runtime.h>
#include <hip/hip_bf16.h>
#include <stdint.h>

#define Bdim 16
#define Ndim 256
#define Kdim 2048
#define Vdim 768
#define Mdim 4096  // B*N

#define BM 256
#define BN 128
#define BK 64
#define NT (Vdim / BK)          // 12 K-tiles
#define ASZ (BM * BK)           // 16384 elems = 32KB
#define BSZ (BN * BK)           // 8192 elems  = 16KB

typedef __attribute__((ext_vector_type(8))) short short8;
typedef __attribute__((ext_vector_type(4))) float f32x4;

struct alignas(8) bf16x4 { __hip_bfloat16 x, y, z, w; };

#define CFENCE asm volatile("" ::: "memory")

__device__ __forceinline__ void gld_lds16(const void* g, void* l) {
    __builtin_amdgcn_global_load_lds((const __attribute__((address_space(1))) void*)g,
                                     (__attribute__((address_space(3))) void*)l, 16, 0, 0);
}

// Fused pre-pass, one wave per row (4 rows/block):
//   rows [0, Mdim)         : inputs -> bf16 Ab + fp32 row sumsq xsq
//   rows [Mdim, Mdim+Kdim) : protos -> bf16 Pb + fp32 row sumsq psq + fp32 copy to out tail
__global__ __launch_bounds__(256) void rowconv_all(const float* __restrict__ x,
                                                   const float* __restrict__ p,
                                                   __hip_bfloat16* __restrict__ Ab,
                                                   __hip_bfloat16* __restrict__ Pb,
                                                   float* __restrict__ xsq,
                                                   float* __restrict__ psq,
                                                   float* __restrict__ proto_out) {
    const int row = blockIdx.x * 4 + (threadIdx.x >> 6);
    const int lane = threadIdx.x & 63;

    const float* src;
    __hip_bfloat16* dstb;
    float* sq;
    float* cpy = nullptr;
    if (row < Mdim) {
        src = x + (size_t)row * Vdim;
        dstb = Ab + (size_t)row * Vdim;
        sq = xsq + row;
    } else {
        const int r = row - Mdim;
        src = p + (size_t)r * Vdim;
        dstb = Pb + (size_t)r * Vdim;
        sq = psq + r;
        cpy = proto_out + (size_t)r * Vdim;
    }

    float s = 0.f;
#pragma unroll
    for (int j = 0; j < Vdim / 256; ++j) {
        float4 v = *reinterpret_cast<const float4*>(src + j * 256 + lane * 4);
        s += v.x * v.x + v.y * v.y + v.z * v.z + v.w * v.w;
        bf16x4 b;
        b.x = __float2bfloat16(v.x); b.y = __float2bfloat16(v.y);
        b.z = __float2bfloat16(v.z); b.w = __float2bfloat16(v.w);
        *reinterpret_cast<bf16x4*>(dstb + j * 256 + lane * 4) = b;
        if (cpy) *reinterpret_cast<float4*>(cpy + j * 256 + lane * 4) = v;
    }
#pragma unroll
    for (int off = 32; off > 0; off >>= 1) s += __shfl_down(s, off);
    if (lane == 0) *sq = s;
}

// 256x128 tile, BK=64, 8 waves (4M x 2N, 64x64 per wave), 3-deep LDS pipeline,
// 2 phases/K-tile (16 MFMA each), counted vmcnt(6), T2 XOR swizzle, T5 setprio,
// T1 XCD-swizzled grid. Fused distance epilogue.
__global__ __launch_bounds__(512) void gemm_dist(const __hip_bfloat16* __restrict__ Ab,
                                                 const __hip_bfloat16* __restrict__ Pb,
                                                 const float* __restrict__ xsq,
                                                 const float* __restrict__ psq,
                                                 float* __restrict__ out) {
    __shared__ __hip_bfloat16 As[3][ASZ];   // 96KB
    __shared__ __hip_bfloat16 Bs[3][BSZ];   // 48KB

    const int t = threadIdx.x;
    const int lane = t & 63;
    const int wave = t >> 6;
    const int wr = wave >> 1;          // 0..3  (M)
    const int wc = wave & 1;           // 0..1  (N)
    const int fr = lane & 15;
    const int g  = lane >> 4;          // 0..3

    // T1: bijective XCD swizzle (256 blocks % 8 == 0)
    const int wg = (blockIdx.x & 7) * 32 + (blockIdx.x >> 3);
    const int bm = wg >> 4;            // 0..15
    const int bn = wg & 15;            // 0..15
    const int m0 = bm * BM, n0 = bn * BN;

    // ---- staging: linear LDS dest, inverse-swizzled per-lane global source (rule #21)
    // issue chunk = 64 rows x 64 cols (8KB); thread t -> row t>>3, linear slot t&7;
    // that slot holds logical col16 (t&7) ^ (row&7).
    const int srow = t >> 3;                         // 0..63
    const int scol = ((t & 7) ^ (srow & 7)) * 8;     // source col element
    const __hip_bfloat16* Ag = Ab + (size_t)(m0 + srow) * Vdim + scol;
    const __hip_bfloat16* Bg = Pb + (size_t)(n0 + srow) * Vdim + scol;
    const int ldsw = (t >> 6) * 512;                 // wave's 1KB slice (elems) of an 8KB chunk

    // ---- swizzled ds_read byte offsets within one buffer
    int offA[4][2], offB[4][2];
#pragma unroll
    for (int i = 0; i < 4; ++i)
#pragma unroll
        for (int s = 0; s < 2; ++s) {
            const int slot = (((s * 4 + g) ^ (fr & 7)) * 16);
            offA[i][s] = (wr * 64 + i * 16 + fr) * 128 + slot;
            offB[i][s] = (wc * 64 + i * 16 + fr) * 128 + slot;
        }

    f32x4 acc[4][4] = {};

    auto stgA = [&](int buf, int kt, int q) {
        gld_lds16(Ag + (size_t)q * 64 * Vdim + kt * BK, (void*)(&As[buf][q * 4096 + ldsw]));
    };
    auto stgB = [&](int buf, int kt, int q) {
        gld_lds16(Bg + (size_t)q * 64 * Vdim + kt * BK, (void*)(&Bs[buf][q * 4096 + ldsw]));
    };

    // ---- prologue: stage K-tiles 0,1,2 (6 issues each, per wave)
#pragma unroll
    for (int p = 0; p < 3; ++p) {
        stgA(p, p, 0); stgA(p, p, 1); stgA(p, p, 2); stgA(p, p, 3);
        stgB(p, p, 0); stgB(p, p, 1);
    }
    asm volatile("s_waitcnt vmcnt(12)" ::: "memory");   // K-tile 0 landed; 1,2 in flight
    __builtin_amdgcn_s_barrier();
    CFENCE;

    int cb = 0, cs = 2;   // compute buffer (kt%3), stage buffer ((kt+2)%3)
    for (int kt = 0; kt < NT; ++kt) {
        const char* Ap = (const char*)&As[cb][0];
        const char* Bp = (const char*)&Bs[cb][0];
        const bool doStage = (kt >= 1 && kt <= NT - 3);   // stages K-tiles 3..11

        // ---- phase 0: all B frags + A frags i=0,1 ; stage 3 ; 16 MFMA
        short8 bq[4][2], a0[2][2];
#pragma unroll
        for (int j = 0; j < 4; ++j)
#pragma unroll
            for (int s = 0; s < 2; ++s)
                bq[j][s] = *reinterpret_cast<const short8*>(Bp + offB[j][s]);
#pragma unroll
        for (int i = 0; i < 2; ++i)
#pragma unroll
            for (int s = 0; s < 2; ++s)
                a0[i][s] = *reinterpret_cast<const short8*>(Ap + offA[i][s]);
        if (doStage) { stgA(cs, kt + 2, 0); stgA(cs, kt + 2, 1); stgA(cs, kt + 2, 2); }
        CFENCE;
        __builtin_amdgcn_s_barrier();
        CFENCE;
        __builtin_amdgcn_s_setprio(1);
#pragma unroll
        for (int s = 0; s < 2; ++s)
#pragma unroll
            for (int i = 0; i < 2; ++i)
#pragma unroll
                for (int j = 0; j < 4; ++j)
                    acc[i][j] = __builtin_amdgcn_mfma_f32_16x16x32_bf16(a0[i][s], bq[j][s], acc[i][j], 0, 0, 0);
        __builtin_amdgcn_s_setprio(0);
        CFENCE;
        __builtin_amdgcn_s_barrier();
        CFENCE;

        // ---- phase 1: A frags i=2,3 ; stage 3 ; 16 MFMA ; counted vmcnt ; barrier
        short8 a1[2][2];
#pragma unroll
        for (int i = 0; i < 2; ++i)
#pragma unroll
            for (int s = 0; s < 2; ++s)
                a1[i][s] = *reinterpret_cast<const short8*>(Ap + offA[i + 2][s]);
        if (doStage) { stgA(cs, kt + 2, 3); stgB(cs, kt + 2, 0); stgB(cs, kt + 2, 1); }
        CFENCE;
        __builtin_amdgcn_s_barrier();
        CFENCE;
        __builtin_amdgcn_s_setprio(1);
#pragma unroll
        for (int s = 0; s < 2; ++s)
#pragma unroll
            for (int i = 0; i < 2; ++i)
#pragma unroll
                for (int j = 0; j < 4; ++j)
                    acc[i + 2][j] = __builtin_amdgcn_mfma_f32_16x16x32_bf16(a1[i][s], bq[j][s], acc[i + 2][j], 0, 0, 0);
        __builtin_amdgcn_s_setprio(0);
        CFENCE;
        // next K-tile's 6 loads must be complete; tile-after-next's 6 stay in flight
        if (kt <= NT - 3)      asm volatile("s_waitcnt vmcnt(6)" ::: "memory");
        else if (kt == NT - 2) asm volatile("s_waitcnt vmcnt(0)" ::: "memory");
        __builtin_amdgcn_s_barrier();
        CFENCE;

        cb = (cb == 2) ? 0 : cb + 1;
        cs = (cs == 2) ? 0 : cs + 1;
    }

    // ---- epilogue: dist = xsq[m] + psq[n] - 2*xp. C/D: col=lane&15, row=(lane>>4)*4+reg.
    const int fq = g;
    float ps[4];
#pragma unroll
    for (int j = 0; j < 4; ++j) ps[j] = psq[n0 + wc * 64 + j * 16 + fr];
#pragma unroll
    for (int i = 0; i < 4; ++i) {
#pragma unroll
        for (int r = 0; r < 4; ++r) {
            const int m = m0 + wr * 64 + i * 16 + fq * 4 + r;
            const float xs = xsq[m];
            float* orow = out + (size_t)m * Kdim + n0 + wc * 64;
#pragma unroll
            for (int j = 0; j < 4; ++j)
                orow[j * 16 + fr] = xs + ps[j] - 2.0f * acc[i][j][r];
        }
    }
}

extern "C" void kernel_launch(void* const* d_in, const int* in_sizes, int n_in,
                              void* d_out, int out_size, void* d_ws, size_t ws_size,
                              hipStream_t stream) {
    const float* x = (const float*)d_in[0];   // (16,256,768) fp32
    const float* p = (const float*)d_in[1];   // (2048,768) fp32
    float* out = (float*)d_out;               // distances (4096x2048) + prototypes (2048x768)

    char* ws = (char*)d_ws;
    __hip_bfloat16* Ab = (__hip_bfloat16*)ws;                        // 6,291,456 B
    __hip_bfloat16* Pb = (__hip_bfloat16*)(ws + 6291456);            // 3,145,728 B
    float* xsq = (float*)(ws + 6291456 + 3145728);                   // 16,384 B
    float* psq = (float*)(ws + 6291456 + 3145728 + 16384);           // 8,192 B

    rowconv_all<<<(Mdim + Kdim) / 4, 256, 0, stream>>>(x, p, Ab, Pb, xsq, psq,
                                                       out + (size_t)Mdim * Kdim);
    gemm_dist<<<(Mdim / BM) * (Kdim / BN), 512, 0, stream>>>(Ab, Pb, xsq, psq, out);
}

// Round 4
// 27.857 us; speedup vs baseline: 1.1885x; 1.1885x over previous
//
#include <hip/hip_runtime.h>
#include <hip/hip_bf16.h>
#include <stdint.h>

#define Kdim 2048
#define Vdim 768
#define Mdim 4096   // B*N = 16*256

#define BM 256
#define BN 128
#define BK 128
#define NT (Vdim / BK)   // 6 K-tiles

typedef __attribute__((ext_vector_type(4))) int  i32x4;
typedef __attribute__((ext_vector_type(16))) int i32x16;

#define CFENCE asm volatile("" ::: "memory")

__device__ __forceinline__ void gld_lds16(const void* g, void* l) {
    __builtin_amdgcn_global_load_lds((const __attribute__((address_space(1))) void*)g,
                                     (__attribute__((address_space(3))) void*)l, 16, 0, 0);
}

// One wave per row (4 rows/block):
//   rows [0, Mdim)         : inputs -> i8 Aq (per-row scale sxa) + fp32 sumsq xsq
//   rows [Mdim, Mdim+Kdim) : protos -> i8 Pq (spa) + psq + fp32 pass-through copy
__global__ __launch_bounds__(256) void rowquant(const float* __restrict__ x,
                                                const float* __restrict__ p,
                                                int8_t* __restrict__ Aq,
                                                int8_t* __restrict__ Pq,
                                                float* __restrict__ xsq,
                                                float* __restrict__ psq,
                                                float* __restrict__ sxa,
                                                float* __restrict__ spa,
                                                float* __restrict__ proto_out) {
    const int row = blockIdx.x * 4 + (threadIdx.x >> 6);
    const int lane = threadIdx.x & 63;

    const float* src;
    int8_t* dq;
    float *sq, *sc, *cpy = nullptr;
    if (row < Mdim) {
        src = x + (size_t)row * Vdim; dq = Aq + (size_t)row * Vdim;
        sq = xsq + row; sc = sxa + row;
    } else {
        const int r = row - Mdim;
        src = p + (size_t)r * Vdim; dq = Pq + (size_t)r * Vdim;
        sq = psq + r; sc = spa + r; cpy = proto_out + (size_t)r * Vdim;
    }

    float4 v[3];
    float s = 0.f, mx = 0.f;
#pragma unroll
    for (int j = 0; j < 3; ++j) {
        v[j] = *reinterpret_cast<const float4*>(src + j * 256 + lane * 4);
        s += v[j].x * v[j].x + v[j].y * v[j].y + v[j].z * v[j].z + v[j].w * v[j].w;
        mx = fmaxf(mx, fmaxf(fmaxf(fabsf(v[j].x), fabsf(v[j].y)),
                             fmaxf(fabsf(v[j].z), fabsf(v[j].w))));
        if (cpy) *reinterpret_cast<float4*>(cpy + j * 256 + lane * 4) = v[j];
    }
#pragma unroll
    for (int off = 32; off > 0; off >>= 1) {
        s += __shfl_xor(s, off);
        mx = fmaxf(mx, __shfl_xor(mx, off));
    }
    mx = fmaxf(mx, 1e-20f);
    const float inv = 127.0f / mx;
#pragma unroll
    for (int j = 0; j < 3; ++j) {
        int q0 = min(127, max(-127, __float2int_rn(v[j].x * inv)));
        int q1 = min(127, max(-127, __float2int_rn(v[j].y * inv)));
        int q2 = min(127, max(-127, __float2int_rn(v[j].z * inv)));
        int q3 = min(127, max(-127, __float2int_rn(v[j].w * inv)));
        int packed = (q0 & 0xff) | ((q1 & 0xff) << 8) | ((q2 & 0xff) << 16) | (q3 << 24);
        *reinterpret_cast<int*>(dq + j * 256 + lane * 4) = packed;
    }
    if (lane == 0) { *sq = s; *sc = mx * (1.0f / 127.0f); }
}

// i8 GEMM: 256x128 tile, BK=128, 8 waves (4M x 2N, 64x64/wave), 32x32x32 i8 MFMA,
// triple-buffered LDS (144KB), counted vmcnt(6), XOR-swizzled LDS (both-sides),
// XCD-swizzled grid. Fused distance epilogue: xsq + psq - 2*sx*sp*acc.
__global__ __launch_bounds__(512) void gemm_dist_i8(const int8_t* __restrict__ Aq,
                                                    const int8_t* __restrict__ Pq,
                                                    const float* __restrict__ xsq,
                                                    const float* __restrict__ psq,
                                                    const float* __restrict__ sxa,
                                                    const float* __restrict__ spa,
                                                    float* __restrict__ out) {
    __shared__ int8_t As[3][BM * BK];   // 3 x 32KB
    __shared__ int8_t Bs[3][BN * BK];   // 3 x 16KB

    const int t = threadIdx.x;
    const int lane = t & 63;
    const int wave = t >> 6;
    const int wr = wave >> 1;      // 0..3 (M)
    const int wc = wave & 1;       // 0..1 (N)
    const int ln31 = lane & 31;
    const int lh = lane >> 5;      // 0..1

    // T1: bijective XCD swizzle (256 blocks % 8 == 0)
    const int wg = (blockIdx.x & 7) * 32 + (blockIdx.x >> 3);
    const int bm = wg >> 4, bn = wg & 15;
    const int m0 = bm * BM, n0 = bn * BN;

    // Staging: linear LDS dest (gld_lds), inverse-swizzled global source.
    // Chunk = 64 rows x 128B; thread t -> row t>>3, physical 16B-slot t&7,
    // which holds logical 16B-col (t&7)^(row&7).
    const int srow = t >> 3;
    const int scol = ((t & 7) ^ (srow & 7)) * 16;   // i8 elements
    const int8_t* Ag = Aq + (size_t)(m0 + srow) * Vdim + scol;
    const int8_t* Bg = Pq + (size_t)(n0 + srow) * Vdim + scol;
    const int ldsw = wave * 1024;   // wave's 1KB slice of an 8KB chunk

    // Swizzled ds_read byte offsets: row r, logical 16B-col k16 -> slot k16^(r&7).
    int offA[2][4], offB[2][4];
#pragma unroll
    for (int mt = 0; mt < 2; ++mt)
#pragma unroll
        for (int ks = 0; ks < 4; ++ks) {
            const int k16 = ks * 2 + lh;
            const int rA = wr * 64 + mt * 32 + ln31;
            const int rB = wc * 64 + mt * 32 + ln31;
            offA[mt][ks] = rA * BK + ((k16 ^ (rA & 7)) * 16);
            offB[mt][ks] = rB * BK + ((k16 ^ (rB & 7)) * 16);
        }

    i32x16 acc[2][2] = {};

    auto stgA = [&](int buf, int kt, int q) {
        gld_lds16(Ag + (size_t)q * 64 * Vdim + kt * BK, (void*)(&As[buf][q * 8192 + ldsw]));
    };
    auto stgB = [&](int buf, int kt, int q) {
        gld_lds16(Bg + (size_t)q * 64 * Vdim + kt * BK, (void*)(&Bs[buf][q * 8192 + ldsw]));
    };

    // Prologue: stage K-tiles 0,1,2 (6 issues each per wave)
#pragma unroll
    for (int pb = 0; pb < 3; ++pb) {
        stgA(pb, pb, 0); stgA(pb, pb, 1); stgA(pb, pb, 2); stgA(pb, pb, 3);
        stgB(pb, pb, 0); stgB(pb, pb, 1);
    }
    asm volatile("s_waitcnt vmcnt(12)" ::: "memory");   // tile 0 landed; 1,2 in flight
    __builtin_amdgcn_s_barrier();
    CFENCE;

    int cb = 0, cs = 2;
    for (int kt = 0; kt < NT; ++kt) {
        const int8_t* Ap = &As[cb][0];
        const int8_t* Bp = &Bs[cb][0];
        const bool doStage = (kt >= 1 && kt <= NT - 3);   // stages tiles 3..5

        // ---- phase 0: all B frags + A row-block 0 ; 8 MFMA
        i32x4 bq[2][4], a0[4];
#pragma unroll
        for (int nt = 0; nt < 2; ++nt)
#pragma unroll
            for (int ks = 0; ks < 4; ++ks)
                bq[nt][ks] = *reinterpret_cast<const i32x4*>(Bp + offB[nt][ks]);
#pragma unroll
        for (int ks = 0; ks < 4; ++ks)
            a0[ks] = *reinterpret_cast<const i32x4*>(Ap + offA[0][ks]);
        if (doStage) { stgA(cs, kt + 2, 0); stgA(cs, kt + 2, 1); stgA(cs, kt + 2, 2); }
        CFENCE;
        __builtin_amdgcn_s_barrier();
        CFENCE;
        __builtin_amdgcn_s_setprio(1);
#pragma unroll
        for (int ks = 0; ks < 4; ++ks)
#pragma unroll
            for (int nt = 0; nt < 2; ++nt)
                acc[0][nt] = __builtin_amdgcn_mfma_i32_32x32x32_i8(a0[ks], bq[nt][ks], acc[0][nt], 0, 0, 0);
        __builtin_amdgcn_s_setprio(0);
        CFENCE;
        __builtin_amdgcn_s_barrier();
        CFENCE;

        // ---- phase 1: A row-block 1 ; 8 MFMA ; counted vmcnt ; barrier
        i32x4 a1[4];
#pragma unroll
        for (int ks = 0; ks < 4; ++ks)
            a1[ks] = *reinterpret_cast<const i32x4*>(Ap + offA[1][ks]);
        if (doStage) { stgA(cs, kt + 2, 3); stgB(cs, kt + 2, 0); stgB(cs, kt + 2, 1); }
        CFENCE;
        __builtin_amdgcn_s_barrier();
        CFENCE;
        __builtin_amdgcn_s_setprio(1);
#pragma unroll
        for (int ks = 0; ks < 4; ++ks)
#pragma unroll
            for (int nt = 0; nt < 2; ++nt)
                acc[1][nt] = __builtin_amdgcn_mfma_i32_32x32x32_i8(a1[ks], bq[nt][ks], acc[1][nt], 0, 0, 0);
        __builtin_amdgcn_s_setprio(0);
        CFENCE;
        if (kt <= NT - 3)      asm volatile("s_waitcnt vmcnt(6)" ::: "memory");
        else if (kt == NT - 2) asm volatile("s_waitcnt vmcnt(0)" ::: "memory");
        __builtin_amdgcn_s_barrier();
        CFENCE;

        cb = (cb == 2) ? 0 : cb + 1;
        cs = (cs == 2) ? 0 : cs + 1;
    }

    // Epilogue. 32x32 C/D layout: col=lane&31, row=(reg&3)+8*(reg>>2)+4*(lane>>5).
    float ps_[2], sp_[2];
    int col_[2];
#pragma unroll
    for (int nt = 0; nt < 2; ++nt) {
        col_[nt] = n0 + wc * 64 + nt * 32 + ln31;
        ps_[nt] = psq[col_[nt]];
        sp_[nt] = spa[col_[nt]];
    }
#pragma unroll
    for (int mt = 0; mt < 2; ++mt)
#pragma unroll
        for (int reg = 0; reg < 16; ++reg) {
            const int row = m0 + wr * 64 + mt * 32 + (reg & 3) + 8 * (reg >> 2) + 4 * lh;
            const float xs = xsq[row];
            const float m2sx = -2.0f * sxa[row];
#pragma unroll
            for (int nt = 0; nt < 2; ++nt)
                out[(size_t)row * Kdim + col_[nt]] =
                    xs + ps_[nt] + m2sx * sp_[nt] * (float)acc[mt][nt][reg];
        }
}

extern "C" void kernel_launch(void* const* d_in, const int* in_sizes, int n_in,
                              void* d_out, int out_size, void* d_ws, size_t ws_size,
                              hipStream_t stream) {
    const float* x = (const float*)d_in[0];   // (16,256,768) fp32
    const float* p = (const float*)d_in[1];   // (2048,768) fp32
    float* out = (float*)d_out;               // distances (4096x2048) + prototypes (2048x768)

    char* ws = (char*)d_ws;
    int8_t* Aq = (int8_t*)ws;                          // 3,145,728 B
    int8_t* Pq = (int8_t*)(ws + 3145728);              // 1,572,864 B
    float* xsq = (float*)(ws + 4718592);               // 16,384 B
    float* psq = (float*)(ws + 4734976);               // 8,192 B
    float* sxa = (float*)(ws + 4743168);               // 16,384 B
    float* spa = (float*)(ws + 4759552);               // 8,192 B

    rowquant<<<(Mdim + Kdim) / 4, 256, 0, stream>>>(x, p, Aq, Pq, xsq, psq, sxa, spa,
                                                    out + (size_t)Mdim * Kdim);
    gemm_dist_i8<<<(Mdim / BM) * (Kdim / BN), 512, 0, stream>>>(Aq, Pq, xsq, psq, sxa, spa, out);
}